// Round 8
// baseline (122.466 us; speedup 1.0000x reference)
//
#include <hip/hip_runtime.h>
#include <hip/hip_bf16.h>
#include <math.h>

// AdditiveAttention: B=4, Q=512, K=512, H=256, fp32.
// scores[b,q,k] = sum_h wv_h * tanh(qp + kp) -> softmax_k -> @V
// tanh(x) = 1 - 2/(1+e^{2x}); sum_h wv_h drops out of softmax.
// e^{2(q+k)} = e^{2q} * e^{2k}: exponentiate projections once (proj kernel).
// 4 h-terms share one rcp: sum wv_i/t_i = num/(t0*t1*t2*t3).
//
// R4: grid-barrier fusion => cross-XCD coherence storm. Two launches.
// R6/R8: spill when LIVE set exceeds VGPR budget; launch_bounds(1024,8)
//        budget is 64 VGPR. Keep live <= ~56, gate on WRITE_SIZE.
// R9: P3 q-sharing one V stream: attn 63 -> 50us (per-CU L2 BW was binding).
// R10: further V traffic cuts NEUTRAL: L2 BW off critical path.
// R11: VOP3P pk_f32 needs all operands as VGPR PAIRS; broadcast via
//      op_sel:[s,..] op_sel_hi:[s,..] on the containing pair.
// R12: packed f32 is ~issue-rate-NEUTRAL on gfx950 (157.3 TF == scalar rate).
//      Math is only ~1/3 of VALU busy; rest is addressing/moves.
// R13: P3 depth-1 V prefetch: 47.1 -> 45.7us.
// R14: P3 h-quad/float4 + fused combine-softmax: 45.7 -> 41.2us.
// R15: (a) ALL-WAVE softmax: wave=(chunk,q) computes chunk-local (m,S),
//      writes UNNORMALIZED e^(x-m_c) to sS; P3 applies scale[q] =
//      e^(m_c - M)/S once per acc at sRed write (flash-style deferred
//      normalization; kills the 4-of-16-wave serial window).
//      (b) tied-operand "+v" asm accumulates (no RA copies on hot accs).

#define B_ 4
#define Q_ 512
#define K_ 512
#define H_ 256
#define QE_ELEMS (B_ * Q_ * H_)           // 524288
#define KE_ELEMS (B_ * H_ * K_)           // 524288

static constexpr float CEXP = 2.8853900817779268f; // 2*log2(e)
static constexpr float LOG2E = 1.4426950408889634f;

typedef float v2f __attribute__((ext_vector_type(2)));
typedef float v4f __attribute__((ext_vector_type(4)));

// d = a*b + c (both lanes, one VOP3P issue)
__device__ __forceinline__ v2f pk_fma(v2f a, v2f b, v2f c) {
    v2f d;
    asm("v_pk_fma_f32 %0, %1, %2, %3" : "=v"(d) : "v"(a), "v"(b), "v"(c));
    return d;
}
// d = {a.x,a.x}*b + c  (broadcast LO word of pair a)
__device__ __forceinline__ v2f pk_fma_l(v2f a, v2f b, v2f c) {
    v2f d;
    asm("v_pk_fma_f32 %0, %1, %2, %3 op_sel:[0,0,0] op_sel_hi:[0,1,1]"
        : "=v"(d) : "v"(a), "v"(b), "v"(c));
    return d;
}
// d = {a.y,a.y}*b + c  (broadcast HI word of pair a)
__device__ __forceinline__ v2f pk_fma_h(v2f a, v2f b, v2f c) {
    v2f d;
    asm("v_pk_fma_f32 %0, %1, %2, %3 op_sel:[1,0,0] op_sel_hi:[1,1,1]"
        : "=v"(d) : "v"(a), "v"(b), "v"(c));
    return d;
}
__device__ __forceinline__ v2f pk_mul(v2f a, v2f b) {
    v2f d;
    asm("v_pk_mul_f32 %0, %1, %2" : "=v"(d) : "v"(a), "v"(b));
    return d;
}
// d = {a.y,a.y}*b  (broadcast HI word of pair a)
__device__ __forceinline__ v2f pk_mul_h(v2f a, v2f b) {
    v2f d;
    asm("v_pk_mul_f32 %0, %1, %2 op_sel:[1,0] op_sel_hi:[1,1]"
        : "=v"(d) : "v"(a), "v"(b));
    return d;
}
// tied accumulates: c += ... (no fresh dst vreg -> no RA copy)
__device__ __forceinline__ void pk_acc(v2f& c, v2f a, v2f b) {   // c += a*b
    asm("v_pk_fma_f32 %0, %1, %2, %0" : "+v"(c) : "v"(a), "v"(b));
}
__device__ __forceinline__ void pk_acc_l(v2f& c, v2f a, v2f b) { // c += {a.x}*b
    asm("v_pk_fma_f32 %0, %1, %2, %0 op_sel:[0,0,0] op_sel_hi:[0,1,1]"
        : "+v"(c) : "v"(a), "v"(b));
}
__device__ __forceinline__ void pk_acc_h(v2f& c, v2f a, v2f b) { // c += {a.y}*b
    asm("v_pk_fma_f32 %0, %1, %2, %0 op_sel:[1,0,0] op_sel_hi:[1,1,1]"
        : "+v"(c) : "v"(a), "v"(b));
}

// ---------------------------------------------------------------------------
// proj_exp: 256 blocks x 1024 thr. Block = one 64x64 output tile; 4 teams of
// 256 thr each reduce a 64-d quarter (double-buffered LDS, reg prefetch);
// LDS combine -> exp2 -> store.  blocks [0,128): qe; [128,256): ke[b][h][k].
// ---------------------------------------------------------------------------
#define PJ_AS(team, buf, dd, row) smem[(((team)*2 + (buf)) * 16 + (dd)) * 68 + (row)]
#define PJ_SS(team, buf, dd, row) smem[8704 + (((team)*2 + (buf)) * 16 + (dd)) * 68 + (row)]

__global__ __launch_bounds__(1024, 4) void proj_exp(
    const float* __restrict__ queries, const float* __restrict__ keys,
    const float* __restrict__ Wq, const float* __restrict__ Wk,
    float* __restrict__ qe, float* __restrict__ ke)
{
    __shared__ __align__(16) float smem[17408];   // 69632 B

    const int bid = blockIdx.x;
    const int team = threadIdx.x >> 8;   // d-quarter 0..3 (64 d each)
    const int tid = threadIdx.x & 255;

    const float* A; const float* S; float* C; int ldc;
    if (bid < 128) {                 // qe: [B*Q=2048 x H=256], 32x4 tiles
        int mt = bid >> 2, nt = bid & 3;
        A = queries + (mt * 64) * H_;
        S = Wq + (nt * 64) * H_;
        C = qe + (mt * 64) * H_ + nt * 64;
        ldc = H_;
    } else {                         // ke: per-b [H=256 x K=512], 4x8 tiles
        int id = bid - 128;
        int b = id >> 5, mt = (id >> 3) & 3, nt = id & 7;
        A = Wk + (mt * 64) * H_;
        S = keys + ((long)(b * K_ + nt * 64)) * H_;
        C = ke + ((long)(b * H_ + mt * 64)) * K_ + nt * 64;
        ldc = K_;
    }

    const int tx = tid & 15;         // n0 = tx*4
    const int ty = tid >> 4;         // m0 = ty*4
    const int ldr = tid >> 2;        // staging row 0..63
    const int ldd = (tid & 3) * 4;   // staging d-offset 0,4,8,12
    const float* GA = A + ldr * H_ + team * 64 + ldd;
    const float* GS = S + ldr * H_ + team * 64 + ldd;

    float4 av = *(const float4*)GA;
    float4 sv = *(const float4*)GS;
    PJ_AS(team, 0, ldd + 0, ldr) = av.x; PJ_AS(team, 0, ldd + 1, ldr) = av.y;
    PJ_AS(team, 0, ldd + 2, ldr) = av.z; PJ_AS(team, 0, ldd + 3, ldr) = av.w;
    PJ_SS(team, 0, ldd + 0, ldr) = sv.x; PJ_SS(team, 0, ldd + 1, ldr) = sv.y;
    PJ_SS(team, 0, ldd + 2, ldr) = sv.z; PJ_SS(team, 0, ldd + 3, ldr) = sv.w;

    float acc[4][4] = {};
#pragma unroll
    for (int c = 0; c < 4; ++c) {    // 4 chunks x 16 d = 64 d per team
        const int cur = c & 1;
        if (c < 3) {                 // register prefetch of next chunk
            av = *(const float4*)(GA + (c + 1) * 16);
            sv = *(const float4*)(GS + (c + 1) * 16);
        }
        __syncthreads();             // buf[cur] writes visible
#pragma unroll
        for (int dd = 0; dd < 16; ++dd) {
            float4 a4 = *(const float4*)&PJ_AS(team, cur, dd, ty * 4);
            float4 b4 = *(const float4*)&PJ_SS(team, cur, dd, tx * 4);
            float am[4] = {a4.x, a4.y, a4.z, a4.w};
            float bn[4] = {b4.x, b4.y, b4.z, b4.w};
#pragma unroll
            for (int i = 0; i < 4; ++i)
#pragma unroll
                for (int j = 0; j < 4; ++j)
                    acc[i][j] = fmaf(am[i], bn[j], acc[i][j]);
        }
        if (c < 3) {                 // fill other buffer (last read 2 iters ago)
            const int nxt = cur ^ 1;
            PJ_AS(team, nxt, ldd + 0, ldr) = av.x;
            PJ_AS(team, nxt, ldd + 1, ldr) = av.y;
            PJ_AS(team, nxt, ldd + 2, ldr) = av.z;
            PJ_AS(team, nxt, ldd + 3, ldr) = av.w;
            PJ_SS(team, nxt, ldd + 0, ldr) = sv.x;
            PJ_SS(team, nxt, ldd + 1, ldr) = sv.y;
            PJ_SS(team, nxt, ldd + 2, ldr) = sv.z;
            PJ_SS(team, nxt, ldd + 3, ldr) = sv.w;
        }
    }

    // combine 4 d-quarter partials via LDS (reuse staging), exp, store
    __syncthreads();                 // all staging reads complete
    if (team > 0) {
        float* Cmb = smem + (team - 1) * 4352;   // 64 x 68 tile
#pragma unroll
        for (int i = 0; i < 4; ++i) {
            float4 o = {acc[i][0], acc[i][1], acc[i][2], acc[i][3]};
            *(float4*)&Cmb[(ty * 4 + i) * 68 + tx * 4] = o;
        }
    }
    __syncthreads();
    if (team == 0) {
#pragma unroll
        for (int i = 0; i < 4; ++i) {
            const int off = (ty * 4 + i) * 68 + tx * 4;
            float4 p1 = *(const float4*)&smem[off];
            float4 p2 = *(const float4*)&smem[4352 + off];
            float4 p3 = *(const float4*)&smem[8704 + off];
            float4 o;
            o.x = __builtin_amdgcn_exp2f(CEXP * (acc[i][0] + p1.x + p2.x + p3.x));
            o.y = __builtin_amdgcn_exp2f(CEXP * (acc[i][1] + p1.y + p2.y + p3.y));
            o.z = __builtin_amdgcn_exp2f(CEXP * (acc[i][2] + p1.z + p2.z + p3.z));
            o.w = __builtin_amdgcn_exp2f(CEXP * (acc[i][3] + p1.w + p2.w + p3.w));
            *(float4*)&C[(ty * 4 + i) * ldc + tx * 4] = o;
        }
    }
}

// ---------------------------------------------------------------------------
// attn: 512 blocks x 1024 thr (16 waves; 64-VGPR budget => 2 blocks/CU).
// XCD-affine: bid%8 -> XCD; XCD pair {2b,2b+1} serves batch b.
// Phase 1: thread = (k-pair, h-quarter); pk math; ALL teams write sP.
// Phase 2 (R15): ALL-WAVE softmax: wave w = (chunk w>>2, q w&3), 128 k each;
//          combine 4 sP partials, chunk-local (m,S) via shuffles; write
//          UNNORMALIZED e^(x-m_c) to sS + (m_c,S_c) to sMS table.
// Phase 3: thread = (h-quad, kq/16); V float4 stream, depth-1 prefetch,
//          tied v2f accs; per-q scale = e^(m_c - M)/S applied at sRed write.
//          16 kq-partials -> sRed[16][4][256] = 64KB LDS reduce.
// ---------------------------------------------------------------------------
__global__ __launch_bounds__(1024, 8) void attn(
    const float* __restrict__ qe, const float* __restrict__ ke,
    const float* __restrict__ values, const float* __restrict__ wv,
    float* __restrict__ out)
{
    const int bid = blockIdx.x;
    const int xcd = bid & 7;
    const int b = xcd >> 1;
    const int q0 = (((bid >> 3) << 1) | (xcd & 1)) * 4;
    const int t = threadIdx.x;

    // LDS: P1/P2 view: sQ[4*256] | wvs[256] | sS[4*512] | sP[4][4*512]
    //      sMS[16][2] (chunk m,S table) lives past the sRed alias region.
    //      P3 reduce view: sRed[16][4][256] = floats [0,16384)
    __shared__ __align__(16) float smem[16416];
    float* sQ  = smem;                   // [4][H_]
    float* wvs = smem + 4 * H_;          // [H_]
    float* sS  = smem + 5 * H_;          // [4][K_]
    float* sP  = smem + 5 * H_ + 4 * K_; // [4][4][K_]
    float* sMS = smem + 16384;           // [16][2]

    sQ[t] = qe[((long)(b * Q_ + q0 + (t >> 8))) * H_ + (t & 255)];
    if (t < H_) wvs[t] = wv[t];
    __syncthreads();

    // ---- Phase 1: scores
    {
        const int k2 = (t & 255) * 2;    // owns k2, k2+1 (contiguous)
        const int g = t >> 8;            // h-quarter: h in [g*64, g*64+64)
        const float* keb = ke + ((long)(b * H_ + g * 64)) * K_ + k2;

        v2f nx0 = *(const v2f*)(keb);
        v2f nx1 = *(const v2f*)(keb + K_);
        v2f nx2 = *(const v2f*)(keb + 2 * K_);
        v2f nx3 = *(const v2f*)(keb + 3 * K_);
        v2f acc[4] = {{0.f,0.f},{0.f,0.f},{0.f,0.f},{0.f,0.f}};
        const v2f one2 = {1.0f, 1.0f};

#pragma unroll 2
        for (int hl = 0; hl < 64; hl += 4) {
            v2f c0 = nx0, c1 = nx1, c2 = nx2, c3 = nx3;
            if (hl < 60) {               // depth-1 prefetch (runtime guard)
                const float* p = keb + (hl + 4) * K_;
                nx0 = *(const v2f*)(p);
                nx1 = *(const v2f*)(p + K_);
                nx2 = *(const v2f*)(p + 2 * K_);
                nx3 = *(const v2f*)(p + 3 * K_);
            }
            const int h = g * 64 + hl;
            v4f w4 = *(const v4f*)&wvs[h];
            const v2f wlo = w4.lo, whi = w4.hi;
#pragma unroll
            for (int q = 0; q < 4; ++q) {
                v4f e = *(const v4f*)&sQ[q * H_ + h];
                const v2f elo = e.lo, ehi = e.hi;
                v2f t0 = pk_fma_l(elo, c0, one2);   // 1 + e.x*c0
                v2f t1 = pk_fma_h(elo, c1, one2);   // 1 + e.y*c1
                v2f t2 = pk_fma_l(ehi, c2, one2);   // 1 + e.z*c2
                v2f t3 = pk_fma_h(ehi, c3, one2);   // 1 + e.w*c3
                v2f d01 = pk_mul(t0, t1);
                v2f d23 = pk_mul(t2, t3);
                v2f n01 = pk_fma_l(wlo, t1, pk_mul_h(wlo, t0)); // w.x*t1 + w.y*t0
                v2f n23 = pk_fma_l(whi, t3, pk_mul_h(whi, t2)); // w.z*t3 + w.w*t2
                v2f num = pk_fma(n01, d23, pk_mul(n23, d01));
                v2f den = pk_mul(d01, d23);
                v2f r;
                r.x = __builtin_amdgcn_rcpf(den.x);
                r.y = __builtin_amdgcn_rcpf(den.y);
                pk_acc(acc[q], num, r);             // tied: acc += num*r
            }
        }

        // ALL teams write partials (combine fused into softmax)
        {
            float* dst = sP + g * 4 * K_;
#pragma unroll
            for (int q = 0; q < 4; ++q)
                *(v2f*)&dst[q * K_ + k2] = acc[q];
        }
    }
    __syncthreads();

    // ---- Phase 3 setup: issue V prefetch FIRST (covers softmax + barrier)
    const int h4 = (t & 63) * 4;     // h-quad owned by this thread
    const int kq = t >> 6;           // k-16th: 32 k
    const int kbeg = kq * 32;
    const float* vb = values + (long)b * K_ * H_ + h4;

    v4f va = *(const v4f*)&vb[(kbeg + 0) * H_];
    v4f vc = *(const v4f*)&vb[(kbeg + 1) * H_];

    // ---- Phase 2: ALL-WAVE softmax. wave w -> (chunk w>>2, q w&3), 128 k
    {
        const int w = t >> 6;
        const int lane = t & 63;
        const int q = w & 3;
        const int k = (w >> 2) * 128 + lane * 2;
        const int idx = q * K_ + k;
        v2f p0 = *(const v2f*)&sP[idx];
        v2f p1 = *(const v2f*)&sP[4 * K_ + idx];
        v2f p2 = *(const v2f*)&sP[8 * K_ + idx];
        v2f p3 = *(const v2f*)&sP[12 * K_ + idx];
        v2f x = (p0 + p1 + p2 + p3) * -2.0f;
        float m = fmaxf(x.x, x.y);
#pragma unroll
        for (int off = 32; off >= 1; off >>= 1) m = fmaxf(m, __shfl_xor(m, off));
        v2f sv;
        sv.x = __builtin_amdgcn_exp2f((x.x - m) * LOG2E);
        sv.y = __builtin_amdgcn_exp2f((x.y - m) * LOG2E);
        float s = sv.x + sv.y;
#pragma unroll
        for (int off = 32; off >= 1; off >>= 1) s += __shfl_xor(s, off);
        *(v2f*)&sS[idx] = sv;            // UNNORMALIZED e^(x - m_chunk)
        if (lane == 0) { sMS[w * 2] = m; sMS[w * 2 + 1] = s; }
    }
    __syncthreads();                     // sS + sMS ready

    // ---- Phase 3: attn @ V with deferred normalization
    {
        // per-q scale = e^(m_mychunk - M) / S   (wave-uniform per thread)
        const int mych = kq >> 2;        // chunk containing this thread's k
        float scale[4];
#pragma unroll
        for (int q = 0; q < 4; ++q) {
            float m0 = sMS[(0 * 4 + q) * 2], s0 = sMS[(0 * 4 + q) * 2 + 1];
            float m1 = sMS[(1 * 4 + q) * 2], s1 = sMS[(1 * 4 + q) * 2 + 1];
            float m2 = sMS[(2 * 4 + q) * 2], s2 = sMS[(2 * 4 + q) * 2 + 1];
            float m3 = sMS[(3 * 4 + q) * 2], s3 = sMS[(3 * 4 + q) * 2 + 1];
            float M = fmaxf(fmaxf(m0, m1), fmaxf(m2, m3));
            float f0 = __builtin_amdgcn_exp2f((m0 - M) * LOG2E);
            float f1 = __builtin_amdgcn_exp2f((m1 - M) * LOG2E);
            float f2 = __builtin_amdgcn_exp2f((m2 - M) * LOG2E);
            float f3 = __builtin_amdgcn_exp2f((m3 - M) * LOG2E);
            float S = fmaf(s0, f0, fmaf(s1, f1, fmaf(s2, f2, s3 * f3)));
            float fm = (mych == 0) ? f0 : (mych == 1) ? f1 : (mych == 2) ? f2 : f3;
            scale[q] = fm / S;
        }

        v2f a0l = {0.f,0.f}, a0h = {0.f,0.f}, a1l = {0.f,0.f}, a1h = {0.f,0.f};
        v2f a2l = {0.f,0.f}, a2h = {0.f,0.f}, a3l = {0.f,0.f}, a3h = {0.f,0.f};
#pragma unroll 1
        for (int k = kbeg; k < kbeg + 32; k += 4) {
            // rows k,k+1 live in va,vc; prefetch rows k+2,k+3 (always valid)
            v4f vd = *(const v4f*)&vb[(k + 2) * H_];
            v4f ve = *(const v4f*)&vb[(k + 3) * H_];
            {
                v2f w0 = *(const v2f*)&sS[0 * K_ + k];  // wave-uniform bcast
                v2f w1 = *(const v2f*)&sS[1 * K_ + k];
                v2f w2 = *(const v2f*)&sS[2 * K_ + k];
                v2f w3 = *(const v2f*)&sS[3 * K_ + k];
                pk_acc_h(a0l, w0, vc.lo); pk_acc_h(a0h, w0, vc.hi);
                pk_acc_l(a0l, w0, va.lo); pk_acc_l(a0h, w0, va.hi);
                pk_acc_h(a1l, w1, vc.lo); pk_acc_h(a1h, w1, vc.hi);
                pk_acc_l(a1l, w1, va.lo); pk_acc_l(a1h, w1, va.hi);
                pk_acc_h(a2l, w2, vc.lo); pk_acc_h(a2h, w2, vc.hi);
                pk_acc_l(a2l, w2, va.lo); pk_acc_l(a2h, w2, va.hi);
                pk_acc_h(a3l, w3, vc.lo); pk_acc_h(a3h, w3, vc.hi);
                pk_acc_l(a3l, w3, va.lo); pk_acc_l(a3h, w3, va.hi);
            }
            if (k + 4 < kbeg + 32) {     // depth-1 prefetch for next iter
                va = *(const v4f*)&vb[(k + 4) * H_];
                vc = *(const v4f*)&vb[(k + 5) * H_];
            }
            {
                v2f w0 = *(const v2f*)&sS[0 * K_ + k + 2];
                v2f w1 = *(const v2f*)&sS[1 * K_ + k + 2];
                v2f w2 = *(const v2f*)&sS[2 * K_ + k + 2];
                v2f w3 = *(const v2f*)&sS[3 * K_ + k + 2];
                pk_acc_h(a0l, w0, ve.lo); pk_acc_h(a0h, w0, ve.hi);
                pk_acc_l(a0l, w0, vd.lo); pk_acc_l(a0h, w0, vd.hi);
                pk_acc_h(a1l, w1, ve.lo); pk_acc_h(a1h, w1, ve.hi);
                pk_acc_l(a1l, w1, vd.lo); pk_acc_l(a1h, w1, vd.hi);
                pk_acc_h(a2l, w2, ve.lo); pk_acc_h(a2h, w2, ve.hi);
                pk_acc_l(a2l, w2, vd.lo); pk_acc_l(a2h, w2, vd.hi);
                pk_acc_h(a3l, w3, ve.lo); pk_acc_h(a3h, w3, ve.hi);
                pk_acc_l(a3l, w3, vd.lo); pk_acc_l(a3h, w3, vd.hi);
            }
        }

        __syncthreads();   // all sS reads done; smem becomes sRed[16][4][256]
        float* sRed = smem;
        {
            v4f o0; o0.lo = a0l * scale[0]; o0.hi = a0h * scale[0];
            v4f o1; o1.lo = a1l * scale[1]; o1.hi = a1h * scale[1];
            v4f o2; o2.lo = a2l * scale[2]; o2.hi = a2h * scale[2];
            v4f o3; o3.lo = a3l * scale[3]; o3.hi = a3h * scale[3];
            *(v4f*)&sRed[(kq * 4 + 0) * 256 + h4] = o0;
            *(v4f*)&sRed[(kq * 4 + 1) * 256 + h4] = o1;
            *(v4f*)&sRed[(kq * 4 + 2) * 256 + h4] = o2;
            *(v4f*)&sRed[(kq * 4 + 3) * 256 + h4] = o3;
        }
        __syncthreads();

        // final reduce: thread t -> output (q = t>>8, h = t&255), 4-way ILP
        const int q = t >> 8;
        const int h = t & 255;
        float s0 = 0.f, s1 = 0.f, s2 = 0.f, s3 = 0.f;
#pragma unroll
        for (int kk = 0; kk < 16; kk += 4) {
            s0 += sRed[((kk + 0) * 4 + q) * 256 + h];
            s1 += sRed[((kk + 1) * 4 + q) * 256 + h];
            s2 += sRed[((kk + 2) * 4 + q) * 256 + h];
            s3 += sRed[((kk + 3) * 4 + q) * 256 + h];
        }
        out[((long)(b * Q_ + q0 + q)) * H_ + h] = (s0 + s1) + (s2 + s3);
    }
}

extern "C" void kernel_launch(void* const* d_in, const int* in_sizes, int n_in,
                              void* d_out, int out_size, void* d_ws, size_t ws_size,
                              hipStream_t stream) {
    const float* queries = (const float*)d_in[0];  // [B,Q,H]
    const float* keys    = (const float*)d_in[1];  // [B,K,H]
    const float* values  = (const float*)d_in[2];  // [B,K,H]
    const float* Wq      = (const float*)d_in[3];  // [H,H]
    const float* Wk      = (const float*)d_in[4];  // [H,H]
    const float* wv      = (const float*)d_in[5];  // [H]
    float* out = (float*)d_out;

    // ws: [qe 2MB][ke 2MB]
    float* qe = (float*)d_ws;
    float* ke = qe + QE_ELEMS;

    proj_exp<<<256, 1024, 0, stream>>>(queries, keys, Wq, Wk, qe, ke);
    attn<<<512, 1024, 0, stream>>>(qe, ke, values, wv, out);
}

// Round 9
// 115.067 us; speedup vs baseline: 1.0643x; 1.0643x over previous
//
#include <hip/hip_runtime.h>
#include <hip/hip_bf16.h>
#include <math.h>

// AdditiveAttention: B=4, Q=512, K=512, H=256, fp32.
// scores[b,q,k] = sum_h wv_h * tanh(qp + kp) -> softmax_k -> @V
// tanh(x) = 1 - 2/(1+e^{2x}); sum_h wv_h drops out of softmax.
// e^{2(q+k)} = e^{2q} * e^{2k}: exponentiate projections once (proj kernel).
// 4 h-terms share one rcp: sum wv_i/t_i = num/(t0*t1*t2*t3).
//
// R4: grid-barrier fusion => cross-XCD coherence storm. Two launches.
// R6/R8/R15: spill when LIVE set exceeds the 64-VGPR budget
//      (launch_bounds(1024,8)). WRITE_SIZE is the spill gate (VGPR_Count
//      counter is unreliable - reads 32 even when spilling).
// R9: P3 q-sharing one V stream: attn 63 -> 50us (per-CU L2 BW was binding).
// R10: further V traffic cuts NEUTRAL: L2 BW off critical path.
// R11: VOP3P pk_f32 needs all operands as VGPR PAIRS; broadcast via
//      op_sel:[s,..] op_sel_hi:[s,..] on the containing pair.
// R12: packed f32 is ~issue-rate-NEUTRAL on gfx950 (157.3 TF == scalar rate).
// R13: P3 depth-1 V prefetch: 47.1 -> 45.7us.
// R14: P3 h-quad/float4 + fused combine-softmax: 45.7 -> 41.2us.
// R15 lesson: scale[] + its temps computed BEFORE the k-loop and V-prefetch
//      hoisted across softmax => live>64 => spill (WRITE 32MB, 53us).
// R16: R15 structure, pressure-fixed: scale computed POST-loop (only needed
//      at sRed write); V prefetch back to pre-barrier placement (R14).

#define B_ 4
#define Q_ 512
#define K_ 512
#define H_ 256
#define QE_ELEMS (B_ * Q_ * H_)           // 524288
#define KE_ELEMS (B_ * H_ * K_)           // 524288

static constexpr float CEXP = 2.8853900817779268f; // 2*log2(e)
static constexpr float LOG2E = 1.4426950408889634f;

typedef float v2f __attribute__((ext_vector_type(2)));
typedef float v4f __attribute__((ext_vector_type(4)));

// d = a*b + c (both lanes, one VOP3P issue)
__device__ __forceinline__ v2f pk_fma(v2f a, v2f b, v2f c) {
    v2f d;
    asm("v_pk_fma_f32 %0, %1, %2, %3" : "=v"(d) : "v"(a), "v"(b), "v"(c));
    return d;
}
// d = {a.x,a.x}*b + c  (broadcast LO word of pair a)
__device__ __forceinline__ v2f pk_fma_l(v2f a, v2f b, v2f c) {
    v2f d;
    asm("v_pk_fma_f32 %0, %1, %2, %3 op_sel:[0,0,0] op_sel_hi:[0,1,1]"
        : "=v"(d) : "v"(a), "v"(b), "v"(c));
    return d;
}
// d = {a.y,a.y}*b + c  (broadcast HI word of pair a)
__device__ __forceinline__ v2f pk_fma_h(v2f a, v2f b, v2f c) {
    v2f d;
    asm("v_pk_fma_f32 %0, %1, %2, %3 op_sel:[1,0,0] op_sel_hi:[1,1,1]"
        : "=v"(d) : "v"(a), "v"(b), "v"(c));
    return d;
}
__device__ __forceinline__ v2f pk_mul(v2f a, v2f b) {
    v2f d;
    asm("v_pk_mul_f32 %0, %1, %2" : "=v"(d) : "v"(a), "v"(b));
    return d;
}
// d = {a.y,a.y}*b  (broadcast HI word of pair a)
__device__ __forceinline__ v2f pk_mul_h(v2f a, v2f b) {
    v2f d;
    asm("v_pk_mul_f32 %0, %1, %2 op_sel:[1,0] op_sel_hi:[1,1]"
        : "=v"(d) : "v"(a), "v"(b));
    return d;
}
// tied accumulates: c += ... (no fresh dst vreg -> no RA copy)
__device__ __forceinline__ void pk_acc(v2f& c, v2f a, v2f b) {   // c += a*b
    asm("v_pk_fma_f32 %0, %1, %2, %0" : "+v"(c) : "v"(a), "v"(b));
}
__device__ __forceinline__ void pk_acc_l(v2f& c, v2f a, v2f b) { // c += {a.x}*b
    asm("v_pk_fma_f32 %0, %1, %2, %0 op_sel:[0,0,0] op_sel_hi:[0,1,1]"
        : "+v"(c) : "v"(a), "v"(b));
}
__device__ __forceinline__ void pk_acc_h(v2f& c, v2f a, v2f b) { // c += {a.y}*b
    asm("v_pk_fma_f32 %0, %1, %2, %0 op_sel:[1,0,0] op_sel_hi:[1,1,1]"
        : "+v"(c) : "v"(a), "v"(b));
}

// ---------------------------------------------------------------------------
// proj_exp: 256 blocks x 1024 thr. Block = one 64x64 output tile; 4 teams of
// 256 thr each reduce a 64-d quarter (double-buffered LDS, reg prefetch);
// LDS combine -> exp2 -> store.  blocks [0,128): qe; [128,256): ke[b][h][k].
// ---------------------------------------------------------------------------
#define PJ_AS(team, buf, dd, row) smem[(((team)*2 + (buf)) * 16 + (dd)) * 68 + (row)]
#define PJ_SS(team, buf, dd, row) smem[8704 + (((team)*2 + (buf)) * 16 + (dd)) * 68 + (row)]

__global__ __launch_bounds__(1024, 4) void proj_exp(
    const float* __restrict__ queries, const float* __restrict__ keys,
    const float* __restrict__ Wq, const float* __restrict__ Wk,
    float* __restrict__ qe, float* __restrict__ ke)
{
    __shared__ __align__(16) float smem[17408];   // 69632 B

    const int bid = blockIdx.x;
    const int team = threadIdx.x >> 8;   // d-quarter 0..3 (64 d each)
    const int tid = threadIdx.x & 255;

    const float* A; const float* S; float* C; int ldc;
    if (bid < 128) {                 // qe: [B*Q=2048 x H=256], 32x4 tiles
        int mt = bid >> 2, nt = bid & 3;
        A = queries + (mt * 64) * H_;
        S = Wq + (nt * 64) * H_;
        C = qe + (mt * 64) * H_ + nt * 64;
        ldc = H_;
    } else {                         // ke: per-b [H=256 x K=512], 4x8 tiles
        int id = bid - 128;
        int b = id >> 5, mt = (id >> 3) & 3, nt = id & 7;
        A = Wk + (mt * 64) * H_;
        S = keys + ((long)(b * K_ + nt * 64)) * H_;
        C = ke + ((long)(b * H_ + mt * 64)) * K_ + nt * 64;
        ldc = K_;
    }

    const int tx = tid & 15;         // n0 = tx*4
    const int ty = tid >> 4;         // m0 = ty*4
    const int ldr = tid >> 2;        // staging row 0..63
    const int ldd = (tid & 3) * 4;   // staging d-offset 0,4,8,12
    const float* GA = A + ldr * H_ + team * 64 + ldd;
    const float* GS = S + ldr * H_ + team * 64 + ldd;

    float4 av = *(const float4*)GA;
    float4 sv = *(const float4*)GS;
    PJ_AS(team, 0, ldd + 0, ldr) = av.x; PJ_AS(team, 0, ldd + 1, ldr) = av.y;
    PJ_AS(team, 0, ldd + 2, ldr) = av.z; PJ_AS(team, 0, ldd + 3, ldr) = av.w;
    PJ_SS(team, 0, ldd + 0, ldr) = sv.x; PJ_SS(team, 0, ldd + 1, ldr) = sv.y;
    PJ_SS(team, 0, ldd + 2, ldr) = sv.z; PJ_SS(team, 0, ldd + 3, ldr) = sv.w;

    float acc[4][4] = {};
#pragma unroll
    for (int c = 0; c < 4; ++c) {    // 4 chunks x 16 d = 64 d per team
        const int cur = c & 1;
        if (c < 3) {                 // register prefetch of next chunk
            av = *(const float4*)(GA + (c + 1) * 16);
            sv = *(const float4*)(GS + (c + 1) * 16);
        }
        __syncthreads();             // buf[cur] writes visible
#pragma unroll
        for (int dd = 0; dd < 16; ++dd) {
            float4 a4 = *(const float4*)&PJ_AS(team, cur, dd, ty * 4);
            float4 b4 = *(const float4*)&PJ_SS(team, cur, dd, tx * 4);
            float am[4] = {a4.x, a4.y, a4.z, a4.w};
            float bn[4] = {b4.x, b4.y, b4.z, b4.w};
#pragma unroll
            for (int i = 0; i < 4; ++i)
#pragma unroll
                for (int j = 0; j < 4; ++j)
                    acc[i][j] = fmaf(am[i], bn[j], acc[i][j]);
        }
        if (c < 3) {                 // fill other buffer (last read 2 iters ago)
            const int nxt = cur ^ 1;
            PJ_AS(team, nxt, ldd + 0, ldr) = av.x;
            PJ_AS(team, nxt, ldd + 1, ldr) = av.y;
            PJ_AS(team, nxt, ldd + 2, ldr) = av.z;
            PJ_AS(team, nxt, ldd + 3, ldr) = av.w;
            PJ_SS(team, nxt, ldd + 0, ldr) = sv.x;
            PJ_SS(team, nxt, ldd + 1, ldr) = sv.y;
            PJ_SS(team, nxt, ldd + 2, ldr) = sv.z;
            PJ_SS(team, nxt, ldd + 3, ldr) = sv.w;
        }
    }

    // combine 4 d-quarter partials via LDS (reuse staging), exp, store
    __syncthreads();                 // all staging reads complete
    if (team > 0) {
        float* Cmb = smem + (team - 1) * 4352;   // 64 x 68 tile
#pragma unroll
        for (int i = 0; i < 4; ++i) {
            float4 o = {acc[i][0], acc[i][1], acc[i][2], acc[i][3]};
            *(float4*)&Cmb[(ty * 4 + i) * 68 + tx * 4] = o;
        }
    }
    __syncthreads();
    if (team == 0) {
#pragma unroll
        for (int i = 0; i < 4; ++i) {
            const int off = (ty * 4 + i) * 68 + tx * 4;
            float4 p1 = *(const float4*)&smem[off];
            float4 p2 = *(const float4*)&smem[4352 + off];
            float4 p3 = *(const float4*)&smem[8704 + off];
            float4 o;
            o.x = __builtin_amdgcn_exp2f(CEXP * (acc[i][0] + p1.x + p2.x + p3.x));
            o.y = __builtin_amdgcn_exp2f(CEXP * (acc[i][1] + p1.y + p2.y + p3.y));
            o.z = __builtin_amdgcn_exp2f(CEXP * (acc[i][2] + p1.z + p2.z + p3.z));
            o.w = __builtin_amdgcn_exp2f(CEXP * (acc[i][3] + p1.w + p2.w + p3.w));
            *(float4*)&C[(ty * 4 + i) * ldc + tx * 4] = o;
        }
    }
}

// ---------------------------------------------------------------------------
// attn: 512 blocks x 1024 thr (16 waves; 64-VGPR budget => 2 blocks/CU).
// XCD-affine: bid%8 -> XCD; XCD pair {2b,2b+1} serves batch b.
// Phase 1: thread = (k-pair, h-quarter); pk math; ALL teams write sP.
// Phase 2: ALL-WAVE softmax: wave w = (chunk w>>2, q w&3), 128 k each;
//          combine 4 sP partials, chunk-local (m,S) via shuffles; write
//          UNNORMALIZED e^(x-m_c) to sS + (m_c,S_c) to sMS table.
// Phase 3: thread = (h-quad, kq/16); V float4 stream, depth-1 prefetch
//          (issued pre-barrier, post-softmax), tied v2f accs; per-q scale =
//          e^(m_c - M)/S computed POST-loop, applied at sRed write.
//          16 kq-partials -> sRed[16][4][256] = 64KB LDS reduce.
// ---------------------------------------------------------------------------
__global__ __launch_bounds__(1024, 8) void attn(
    const float* __restrict__ qe, const float* __restrict__ ke,
    const float* __restrict__ values, const float* __restrict__ wv,
    float* __restrict__ out)
{
    const int bid = blockIdx.x;
    const int xcd = bid & 7;
    const int b = xcd >> 1;
    const int q0 = (((bid >> 3) << 1) | (xcd & 1)) * 4;
    const int t = threadIdx.x;

    // LDS: P1/P2 view: sQ[4*256] | wvs[256] | sS[4*512] | sP[4][4*512]
    //      sMS[16][2] (chunk m,S table) lives past the sRed alias region.
    //      P3 reduce view: sRed[16][4][256] = floats [0,16384)
    __shared__ __align__(16) float smem[16416];
    float* sQ  = smem;                   // [4][H_]
    float* wvs = smem + 4 * H_;          // [H_]
    float* sS  = smem + 5 * H_;          // [4][K_]
    float* sP  = smem + 5 * H_ + 4 * K_; // [4][4][K_]
    float* sMS = smem + 16384;           // [16][2]

    sQ[t] = qe[((long)(b * Q_ + q0 + (t >> 8))) * H_ + (t & 255)];
    if (t < H_) wvs[t] = wv[t];
    __syncthreads();

    // ---- Phase 1: scores
    {
        const int k2 = (t & 255) * 2;    // owns k2, k2+1 (contiguous)
        const int g = t >> 8;            // h-quarter: h in [g*64, g*64+64)
        const float* keb = ke + ((long)(b * H_ + g * 64)) * K_ + k2;

        v2f nx0 = *(const v2f*)(keb);
        v2f nx1 = *(const v2f*)(keb + K_);
        v2f nx2 = *(const v2f*)(keb + 2 * K_);
        v2f nx3 = *(const v2f*)(keb + 3 * K_);
        v2f acc[4] = {{0.f,0.f},{0.f,0.f},{0.f,0.f},{0.f,0.f}};
        const v2f one2 = {1.0f, 1.0f};

#pragma unroll 2
        for (int hl = 0; hl < 64; hl += 4) {
            v2f c0 = nx0, c1 = nx1, c2 = nx2, c3 = nx3;
            if (hl < 60) {               // depth-1 prefetch (runtime guard)
                const float* p = keb + (hl + 4) * K_;
                nx0 = *(const v2f*)(p);
                nx1 = *(const v2f*)(p + K_);
                nx2 = *(const v2f*)(p + 2 * K_);
                nx3 = *(const v2f*)(p + 3 * K_);
            }
            const int h = g * 64 + hl;
            v4f w4 = *(const v4f*)&wvs[h];
            const v2f wlo = w4.lo, whi = w4.hi;
#pragma unroll
            for (int q = 0; q < 4; ++q) {
                v4f e = *(const v4f*)&sQ[q * H_ + h];
                const v2f elo = e.lo, ehi = e.hi;
                v2f t0 = pk_fma_l(elo, c0, one2);   // 1 + e.x*c0
                v2f t1 = pk_fma_h(elo, c1, one2);   // 1 + e.y*c1
                v2f t2 = pk_fma_l(ehi, c2, one2);   // 1 + e.z*c2
                v2f t3 = pk_fma_h(ehi, c3, one2);   // 1 + e.w*c3
                v2f d01 = pk_mul(t0, t1);
                v2f d23 = pk_mul(t2, t3);
                v2f n01 = pk_fma_l(wlo, t1, pk_mul_h(wlo, t0)); // w.x*t1 + w.y*t0
                v2f n23 = pk_fma_l(whi, t3, pk_mul_h(whi, t2)); // w.z*t3 + w.w*t2
                v2f num = pk_fma(n01, d23, pk_mul(n23, d01));
                v2f den = pk_mul(d01, d23);
                v2f r;
                r.x = __builtin_amdgcn_rcpf(den.x);
                r.y = __builtin_amdgcn_rcpf(den.y);
                pk_acc(acc[q], num, r);             // tied: acc += num*r
            }
        }

        // ALL teams write partials (combine fused into softmax)
        {
            float* dst = sP + g * 4 * K_;
#pragma unroll
            for (int q = 0; q < 4; ++q)
                *(v2f*)&dst[q * K_ + k2] = acc[q];
        }
    }
    __syncthreads();

    // ---- Phase 2: ALL-WAVE softmax. wave w -> (chunk w>>2, q w&3), 128 k
    {
        const int w = t >> 6;
        const int lane = t & 63;
        const int q = w & 3;
        const int k = (w >> 2) * 128 + lane * 2;
        const int idx = q * K_ + k;
        v2f p0 = *(const v2f*)&sP[idx];
        v2f p1 = *(const v2f*)&sP[4 * K_ + idx];
        v2f p2 = *(const v2f*)&sP[8 * K_ + idx];
        v2f p3 = *(const v2f*)&sP[12 * K_ + idx];
        v2f x = (p0 + p1 + p2 + p3) * -2.0f;
        float m = fmaxf(x.x, x.y);
#pragma unroll
        for (int off = 32; off >= 1; off >>= 1) m = fmaxf(m, __shfl_xor(m, off));
        v2f sv;
        sv.x = __builtin_amdgcn_exp2f((x.x - m) * LOG2E);
        sv.y = __builtin_amdgcn_exp2f((x.y - m) * LOG2E);
        float s = sv.x + sv.y;
#pragma unroll
        for (int off = 32; off >= 1; off >>= 1) s += __shfl_xor(s, off);
        *(v2f*)&sS[idx] = sv;            // UNNORMALIZED e^(x - m_chunk)
        if (lane == 0) { sMS[w * 2] = m; sMS[w * 2 + 1] = s; }
    }

    // ---- Phase 3 setup: V prefetch issued pre-barrier (R14 placement)
    const int h4 = (t & 63) * 4;     // h-quad owned by this thread
    const int kq = t >> 6;           // k-16th: 32 k
    const int kbeg = kq * 32;
    const float* vb = values + (long)b * K_ * H_ + h4;

    v4f va = *(const v4f*)&vb[(kbeg + 0) * H_];
    v4f vc = *(const v4f*)&vb[(kbeg + 1) * H_];

    __syncthreads();                     // sS + sMS ready

    // ---- Phase 3: attn @ V with deferred normalization
    {
        v2f a0l = {0.f,0.f}, a0h = {0.f,0.f}, a1l = {0.f,0.f}, a1h = {0.f,0.f};
        v2f a2l = {0.f,0.f}, a2h = {0.f,0.f}, a3l = {0.f,0.f}, a3h = {0.f,0.f};
#pragma unroll 1
        for (int k = kbeg; k < kbeg + 32; k += 4) {
            // rows k,k+1 live in va,vc; prefetch rows k+2,k+3 (always valid)
            v4f vd = *(const v4f*)&vb[(k + 2) * H_];
            v4f ve = *(const v4f*)&vb[(k + 3) * H_];
            {
                v2f w0 = *(const v2f*)&sS[0 * K_ + k];  // wave-uniform bcast
                v2f w1 = *(const v2f*)&sS[1 * K_ + k];
                v2f w2 = *(const v2f*)&sS[2 * K_ + k];
                v2f w3 = *(const v2f*)&sS[3 * K_ + k];
                pk_acc_h(a0l, w0, vc.lo); pk_acc_h(a0h, w0, vc.hi);
                pk_acc_l(a0l, w0, va.lo); pk_acc_l(a0h, w0, va.hi);
                pk_acc_h(a1l, w1, vc.lo); pk_acc_h(a1h, w1, vc.hi);
                pk_acc_l(a1l, w1, va.lo); pk_acc_l(a1h, w1, va.hi);
                pk_acc_h(a2l, w2, vc.lo); pk_acc_h(a2h, w2, vc.hi);
                pk_acc_l(a2l, w2, va.lo); pk_acc_l(a2h, w2, va.hi);
                pk_acc_h(a3l, w3, vc.lo); pk_acc_h(a3h, w3, vc.hi);
                pk_acc_l(a3l, w3, va.lo); pk_acc_l(a3h, w3, va.hi);
            }
            if (k + 4 < kbeg + 32) {     // depth-1 prefetch for next iter
                va = *(const v4f*)&vb[(k + 4) * H_];
                vc = *(const v4f*)&vb[(k + 5) * H_];
            }
            {
                v2f w0 = *(const v2f*)&sS[0 * K_ + k + 2];
                v2f w1 = *(const v2f*)&sS[1 * K_ + k + 2];
                v2f w2 = *(const v2f*)&sS[2 * K_ + k + 2];
                v2f w3 = *(const v2f*)&sS[3 * K_ + k + 2];
                pk_acc_h(a0l, w0, ve.lo); pk_acc_h(a0h, w0, ve.hi);
                pk_acc_l(a0l, w0, vd.lo); pk_acc_l(a0h, w0, vd.hi);
                pk_acc_h(a1l, w1, ve.lo); pk_acc_h(a1h, w1, ve.hi);
                pk_acc_l(a1l, w1, vd.lo); pk_acc_l(a1h, w1, vd.hi);
                pk_acc_h(a2l, w2, ve.lo); pk_acc_h(a2h, w2, ve.hi);
                pk_acc_l(a2l, w2, vd.lo); pk_acc_l(a2h, w2, vd.hi);
                pk_acc_h(a3l, w3, ve.lo); pk_acc_h(a3h, w3, ve.hi);
                pk_acc_l(a3l, w3, vd.lo); pk_acc_l(a3h, w3, vd.hi);
            }
        }

        // POST-loop: per-q scale = e^(m_mychunk - M)/S (wave-uniform; ~14
        // temps live here, accs only other live state - no loop pressure)
        const int mych = kq >> 2;
        float scale[4];
#pragma unroll
        for (int q = 0; q < 4; ++q) {
            float m0 = sMS[(0 * 4 + q) * 2], s0 = sMS[(0 * 4 + q) * 2 + 1];
            float m1 = sMS[(1 * 4 + q) * 2], s1 = sMS[(1 * 4 + q) * 2 + 1];
            float m2 = sMS[(2 * 4 + q) * 2], s2 = sMS[(2 * 4 + q) * 2 + 1];
            float m3 = sMS[(3 * 4 + q) * 2], s3 = sMS[(3 * 4 + q) * 2 + 1];
            float M = fmaxf(fmaxf(m0, m1), fmaxf(m2, m3));
            float f0 = __builtin_amdgcn_exp2f((m0 - M) * LOG2E);
            float f1 = __builtin_amdgcn_exp2f((m1 - M) * LOG2E);
            float f2 = __builtin_amdgcn_exp2f((m2 - M) * LOG2E);
            float f3 = __builtin_amdgcn_exp2f((m3 - M) * LOG2E);
            float S = fmaf(s0, f0, fmaf(s1, f1, fmaf(s2, f2, s3 * f3)));
            float fm = (mych == 0) ? f0 : (mych == 1) ? f1 : (mych == 2) ? f2 : f3;
            scale[q] = fm / S;
        }

        __syncthreads();   // all sS reads done; smem becomes sRed[16][4][256]
        float* sRed = smem;
        {
            v4f o0; o0.lo = a0l * scale[0]; o0.hi = a0h * scale[0];
            v4f o1; o1.lo = a1l * scale[1]; o1.hi = a1h * scale[1];
            v4f o2; o2.lo = a2l * scale[2]; o2.hi = a2h * scale[2];
            v4f o3; o3.lo = a3l * scale[3]; o3.hi = a3h * scale[3];
            *(v4f*)&sRed[(kq * 4 + 0) * 256 + h4] = o0;
            *(v4f*)&sRed[(kq * 4 + 1) * 256 + h4] = o1;
            *(v4f*)&sRed[(kq * 4 + 2) * 256 + h4] = o2;
            *(v4f*)&sRed[(kq * 4 + 3) * 256 + h4] = o3;
        }
        __syncthreads();

        // final reduce: thread t -> output (q = t>>8, h = t&255), 4-way ILP
        const int q = t >> 8;
        const int h = t & 255;
        float s0 = 0.f, s1 = 0.f, s2 = 0.f, s3 = 0.f;
#pragma unroll
        for (int kk = 0; kk < 16; kk += 4) {
            s0 += sRed[((kk + 0) * 4 + q) * 256 + h];
            s1 += sRed[((kk + 1) * 4 + q) * 256 + h];
            s2 += sRed[((kk + 2) * 4 + q) * 256 + h];
            s3 += sRed[((kk + 3) * 4 + q) * 256 + h];
        }
        out[((long)(b * Q_ + q0 + q)) * H_ + h] = (s0 + s1) + (s2 + s3);
    }
}

extern "C" void kernel_launch(void* const* d_in, const int* in_sizes, int n_in,
                              void* d_out, int out_size, void* d_ws, size_t ws_size,
                              hipStream_t stream) {
    const float* queries = (const float*)d_in[0];  // [B,Q,H]
    const float* keys    = (const float*)d_in[1];  // [B,K,H]
    const float* values  = (const float*)d_in[2];  // [B,K,H]
    const float* Wq      = (const float*)d_in[3];  // [H,H]
    const float* Wk      = (const float*)d_in[4];  // [H,H]
    const float* wv      = (const float*)d_in[5];  // [H]
    float* out = (float*)d_out;

    // ws: [qe 2MB][ke 2MB]
    float* qe = (float*)d_ws;
    float* ke = qe + QE_ELEMS;

    proj_exp<<<256, 1024, 0, stream>>>(queries, keys, Wq, Wk, qe, ke);
    attn<<<512, 1024, 0, stream>>>(qe, ke, values, wv, out);
}

// Round 10
// 110.649 us; speedup vs baseline: 1.1068x; 1.0399x over previous
//
#include <hip/hip_runtime.h>
#include <hip/hip_bf16.h>
#include <math.h>

// AdditiveAttention: B=4, Q=512, K=512, H=256, fp32.
// scores[b,q,k] = sum_h wv_h * tanh(qp + kp) -> softmax_k -> @V
// tanh(x) = 1 - 2/(1+e^{2x}); sum_h wv_h drops out of softmax.
// e^{2(q+k)} = e^{2q} * e^{2k}: exponentiate projections once (proj kernel).
// 4 h-terms share one rcp: sum wv_i/t_i = num/(t0*t1*t2*t3).
//
// R4: grid-barrier fusion => cross-XCD coherence storm. Two launches.
// R6/R8/R15: spill when LIVE set exceeds the VGPR budget; (1024,8) => 64.
//      WRITE_SIZE is the spill gate (VGPR_Count counter unreliable).
// R9: P3 q-sharing one V stream: attn 63 -> 50us (per-CU L2 BW was binding).
// R10: further V traffic cuts NEUTRAL: L2 BW off critical path.
// R11: VOP3P pk_f32 needs all operands as VGPR PAIRS; broadcast via
//      op_sel:[s,..] op_sel_hi:[s,..] on the containing pair.
// R12: packed f32 is ~issue-rate-NEUTRAL on gfx950 but halves inst count;
//      small win (~2us on attn P1).
// R13: P3 depth-1 V prefetch: 47.1 -> 45.7us.
// R14: P3 h-quad/float4 + fused combine-softmax: 45.7 -> 41.2us.  KEEPER.
// R15/R16 lesson: all-wave softmax + deferred normalization costs MORE than
//      the 4-wave serial softmax window it removes (44.0 vs 41.2 clean A/B).
//      Reverted to R14 attn.
// R17: proj_exp inner loop pk-ified (8 pk_acc per dd vs 16 scalar fma,
//      bit-identical math) - proj was the last scalar-issue-bound kernel.

#define B_ 4
#define Q_ 512
#define K_ 512
#define H_ 256
#define QE_ELEMS (B_ * Q_ * H_)           // 524288
#define KE_ELEMS (B_ * H_ * K_)           // 524288

static constexpr float CEXP = 2.8853900817779268f; // 2*log2(e)
static constexpr float LOG2E = 1.4426950408889634f;

typedef float v2f __attribute__((ext_vector_type(2)));
typedef float v4f __attribute__((ext_vector_type(4)));

// d = a*b + c (both lanes, one VOP3P issue)
__device__ __forceinline__ v2f pk_fma(v2f a, v2f b, v2f c) {
    v2f d;
    asm("v_pk_fma_f32 %0, %1, %2, %3" : "=v"(d) : "v"(a), "v"(b), "v"(c));
    return d;
}
// d = {a.x,a.x}*b + c  (broadcast LO word of pair a)
__device__ __forceinline__ v2f pk_fma_l(v2f a, v2f b, v2f c) {
    v2f d;
    asm("v_pk_fma_f32 %0, %1, %2, %3 op_sel:[0,0,0] op_sel_hi:[0,1,1]"
        : "=v"(d) : "v"(a), "v"(b), "v"(c));
    return d;
}
// d = {a.y,a.y}*b + c  (broadcast HI word of pair a)
__device__ __forceinline__ v2f pk_fma_h(v2f a, v2f b, v2f c) {
    v2f d;
    asm("v_pk_fma_f32 %0, %1, %2, %3 op_sel:[1,0,0] op_sel_hi:[1,1,1]"
        : "=v"(d) : "v"(a), "v"(b), "v"(c));
    return d;
}
__device__ __forceinline__ v2f pk_mul(v2f a, v2f b) {
    v2f d;
    asm("v_pk_mul_f32 %0, %1, %2" : "=v"(d) : "v"(a), "v"(b));
    return d;
}
// d = {a.y,a.y}*b  (broadcast HI word of pair a)
__device__ __forceinline__ v2f pk_mul_h(v2f a, v2f b) {
    v2f d;
    asm("v_pk_mul_f32 %0, %1, %2 op_sel:[1,0] op_sel_hi:[1,1]"
        : "=v"(d) : "v"(a), "v"(b));
    return d;
}
// float4 forms: broadcast scalar (lo/hi word of pair a) across both halves
__device__ __forceinline__ v4f pk4_fma_l(v2f a, v4f b, v4f c) {
    v4f d;
    d.lo = pk_fma_l(a, b.lo, c.lo);
    d.hi = pk_fma_l(a, b.hi, c.hi);
    return d;
}
__device__ __forceinline__ v4f pk4_fma_h(v2f a, v4f b, v4f c) {
    v4f d;
    d.lo = pk_fma_h(a, b.lo, c.lo);
    d.hi = pk_fma_h(a, b.hi, c.hi);
    return d;
}
// tied accumulates: c += ... (no fresh dst vreg -> no RA copy)
__device__ __forceinline__ void pk_acc_l(v2f& c, v2f a, v2f b) { // c += {a.x}*b
    asm("v_pk_fma_f32 %0, %1, %2, %0 op_sel:[0,0,0] op_sel_hi:[0,1,1]"
        : "+v"(c) : "v"(a), "v"(b));
}
__device__ __forceinline__ void pk_acc_h(v2f& c, v2f a, v2f b) { // c += {a.y}*b
    asm("v_pk_fma_f32 %0, %1, %2, %0 op_sel:[1,0,0] op_sel_hi:[1,1,1]"
        : "+v"(c) : "v"(a), "v"(b));
}

// ---------------------------------------------------------------------------
// proj_exp: 256 blocks x 1024 thr. Block = one 64x64 output tile; 4 teams of
// 256 thr each reduce a 64-d quarter (double-buffered LDS, reg prefetch);
// LDS combine -> exp2 -> store.  blocks [0,128): qe; [128,256): ke[b][h][k].
// R17: inner 4x4 accumulate as 8 pk_acc (acc2[i][jp].x/.y = acc[i][2jp/2jp+1]).
// ---------------------------------------------------------------------------
#define PJ_AS(team, buf, dd, row) smem[(((team)*2 + (buf)) * 16 + (dd)) * 68 + (row)]
#define PJ_SS(team, buf, dd, row) smem[8704 + (((team)*2 + (buf)) * 16 + (dd)) * 68 + (row)]

__global__ __launch_bounds__(1024, 4) void proj_exp(
    const float* __restrict__ queries, const float* __restrict__ keys,
    const float* __restrict__ Wq, const float* __restrict__ Wk,
    float* __restrict__ qe, float* __restrict__ ke)
{
    __shared__ __align__(16) float smem[17408];   // 69632 B

    const int bid = blockIdx.x;
    const int team = threadIdx.x >> 8;   // d-quarter 0..3 (64 d each)
    const int tid = threadIdx.x & 255;

    const float* A; const float* S; float* C; int ldc;
    if (bid < 128) {                 // qe: [B*Q=2048 x H=256], 32x4 tiles
        int mt = bid >> 2, nt = bid & 3;
        A = queries + (mt * 64) * H_;
        S = Wq + (nt * 64) * H_;
        C = qe + (mt * 64) * H_ + nt * 64;
        ldc = H_;
    } else {                         // ke: per-b [H=256 x K=512], 4x8 tiles
        int id = bid - 128;
        int b = id >> 5, mt = (id >> 3) & 3, nt = id & 7;
        A = Wk + (mt * 64) * H_;
        S = keys + ((long)(b * K_ + nt * 64)) * H_;
        C = ke + ((long)(b * H_ + mt * 64)) * K_ + nt * 64;
        ldc = K_;
    }

    const int tx = tid & 15;         // n0 = tx*4
    const int ty = tid >> 4;         // m0 = ty*4
    const int ldr = tid >> 2;        // staging row 0..63
    const int ldd = (tid & 3) * 4;   // staging d-offset 0,4,8,12
    const float* GA = A + ldr * H_ + team * 64 + ldd;
    const float* GS = S + ldr * H_ + team * 64 + ldd;

    float4 av = *(const float4*)GA;
    float4 sv = *(const float4*)GS;
    PJ_AS(team, 0, ldd + 0, ldr) = av.x; PJ_AS(team, 0, ldd + 1, ldr) = av.y;
    PJ_AS(team, 0, ldd + 2, ldr) = av.z; PJ_AS(team, 0, ldd + 3, ldr) = av.w;
    PJ_SS(team, 0, ldd + 0, ldr) = sv.x; PJ_SS(team, 0, ldd + 1, ldr) = sv.y;
    PJ_SS(team, 0, ldd + 2, ldr) = sv.z; PJ_SS(team, 0, ldd + 3, ldr) = sv.w;

    v2f acc2[4][2] = {};             // acc2[i][jp] = {acc[i][2jp], acc[i][2jp+1]}
#pragma unroll
    for (int c = 0; c < 4; ++c) {    // 4 chunks x 16 d = 64 d per team
        const int cur = c & 1;
        if (c < 3) {                 // register prefetch of next chunk
            av = *(const float4*)(GA + (c + 1) * 16);
            sv = *(const float4*)(GS + (c + 1) * 16);
        }
        __syncthreads();             // buf[cur] writes visible
#pragma unroll
        for (int dd = 0; dd < 16; ++dd) {
            v4f a4 = *(const v4f*)&PJ_AS(team, cur, dd, ty * 4);
            v4f b4 = *(const v4f*)&PJ_SS(team, cur, dd, tx * 4);
            const v2f alo = a4.lo, ahi = a4.hi;
            const v2f blo = b4.lo, bhi = b4.hi;
            pk_acc_l(acc2[0][0], alo, blo); pk_acc_l(acc2[0][1], alo, bhi);
            pk_acc_h(acc2[1][0], alo, blo); pk_acc_h(acc2[1][1], alo, bhi);
            pk_acc_l(acc2[2][0], ahi, blo); pk_acc_l(acc2[2][1], ahi, bhi);
            pk_acc_h(acc2[3][0], ahi, blo); pk_acc_h(acc2[3][1], ahi, bhi);
        }
        if (c < 3) {                 // fill other buffer (last read 2 iters ago)
            const int nxt = cur ^ 1;
            PJ_AS(team, nxt, ldd + 0, ldr) = av.x;
            PJ_AS(team, nxt, ldd + 1, ldr) = av.y;
            PJ_AS(team, nxt, ldd + 2, ldr) = av.z;
            PJ_AS(team, nxt, ldd + 3, ldr) = av.w;
            PJ_SS(team, nxt, ldd + 0, ldr) = sv.x;
            PJ_SS(team, nxt, ldd + 1, ldr) = sv.y;
            PJ_SS(team, nxt, ldd + 2, ldr) = sv.z;
            PJ_SS(team, nxt, ldd + 3, ldr) = sv.w;
        }
    }

    // combine 4 d-quarter partials via LDS (reuse staging), exp, store
    __syncthreads();                 // all staging reads complete
    if (team > 0) {
        float* Cmb = smem + (team - 1) * 4352;   // 64 x 68 tile
#pragma unroll
        for (int i = 0; i < 4; ++i) {
            float4 o = {acc2[i][0].x, acc2[i][0].y, acc2[i][1].x, acc2[i][1].y};
            *(float4*)&Cmb[(ty * 4 + i) * 68 + tx * 4] = o;
        }
    }
    __syncthreads();
    if (team == 0) {
#pragma unroll
        for (int i = 0; i < 4; ++i) {
            const int off = (ty * 4 + i) * 68 + tx * 4;
            float4 p1 = *(const float4*)&smem[off];
            float4 p2 = *(const float4*)&smem[4352 + off];
            float4 p3 = *(const float4*)&smem[8704 + off];
            float4 o;
            o.x = __builtin_amdgcn_exp2f(CEXP * (acc2[i][0].x + p1.x + p2.x + p3.x));
            o.y = __builtin_amdgcn_exp2f(CEXP * (acc2[i][0].y + p1.y + p2.y + p3.y));
            o.z = __builtin_amdgcn_exp2f(CEXP * (acc2[i][1].x + p1.z + p2.z + p3.z));
            o.w = __builtin_amdgcn_exp2f(CEXP * (acc2[i][1].y + p1.w + p2.w + p3.w));
            *(float4*)&C[(ty * 4 + i) * ldc + tx * 4] = o;
        }
    }
}

// ---------------------------------------------------------------------------
// attn (R14 KEEPER, 41.2us): 512 blocks x 1024 thr (16 waves; 64-VGPR
// budget => 2 blocks/CU). XCD-affine: bid%8 -> XCD; pair {2b,2b+1} = batch b.
// Phase 1: thread = (k-pair, h-quarter); pk math; ALL teams write sP.
// Phase 2: fused combine+softmax: wave w<4 -> q row w, reads 4 sP partials.
// Phase 3: thread = (h-quad, kq/16); float4 V stream, named-reg depth-1
//          prefetch; 16 kq-partials -> sRed[16][4][256] = 64KB LDS reduce.
// ---------------------------------------------------------------------------
__global__ __launch_bounds__(1024, 8) void attn(
    const float* __restrict__ qe, const float* __restrict__ ke,
    const float* __restrict__ values, const float* __restrict__ wv,
    float* __restrict__ out)
{
    const int bid = blockIdx.x;
    const int xcd = bid & 7;
    const int b = xcd >> 1;
    const int q0 = (((bid >> 3) << 1) | (xcd & 1)) * 4;
    const int t = threadIdx.x;

    // flat LDS 64KB. P1/P2 view: sQ[4*256] | wvs[256] | sS[4*512] | sP[4][4*512]
    //                P3 reduce view: sRed[16][4][256] (aliases everything)
    __shared__ __align__(16) float smem[16384];
    float* sQ  = smem;                   // [4][H_]
    float* wvs = smem + 4 * H_;          // [H_]
    float* sS  = smem + 5 * H_;          // [4][K_]
    float* sP  = smem + 5 * H_ + 4 * K_; // [4][4][K_]

    sQ[t] = qe[((long)(b * Q_ + q0 + (t >> 8))) * H_ + (t & 255)];
    if (t < H_) wvs[t] = wv[t];
    __syncthreads();

    // ---- Phase 1: scores
    {
        const int k2 = (t & 255) * 2;    // owns k2, k2+1 (contiguous)
        const int g = t >> 8;            // h-quarter: h in [g*64, g*64+64)
        const float* keb = ke + ((long)(b * H_ + g * 64)) * K_ + k2;

        v2f nx0 = *(const v2f*)(keb);
        v2f nx1 = *(const v2f*)(keb + K_);
        v2f nx2 = *(const v2f*)(keb + 2 * K_);
        v2f nx3 = *(const v2f*)(keb + 3 * K_);
        v2f acc[4] = {{0.f,0.f},{0.f,0.f},{0.f,0.f},{0.f,0.f}};
        const v2f one2 = {1.0f, 1.0f};

#pragma unroll 2
        for (int hl = 0; hl < 64; hl += 4) {
            v2f c0 = nx0, c1 = nx1, c2 = nx2, c3 = nx3;
            if (hl < 60) {               // depth-1 prefetch (runtime guard)
                const float* p = keb + (hl + 4) * K_;
                nx0 = *(const v2f*)(p);
                nx1 = *(const v2f*)(p + K_);
                nx2 = *(const v2f*)(p + 2 * K_);
                nx3 = *(const v2f*)(p + 3 * K_);
            }
            const int h = g * 64 + hl;
            v4f w4 = *(const v4f*)&wvs[h];
            const v2f wlo = w4.lo, whi = w4.hi;
#pragma unroll
            for (int q = 0; q < 4; ++q) {
                v4f e = *(const v4f*)&sQ[q * H_ + h];
                const v2f elo = e.lo, ehi = e.hi;
                v2f t0 = pk_fma_l(elo, c0, one2);   // 1 + e.x*c0
                v2f t1 = pk_fma_h(elo, c1, one2);   // 1 + e.y*c1
                v2f t2 = pk_fma_l(ehi, c2, one2);   // 1 + e.z*c2
                v2f t3 = pk_fma_h(ehi, c3, one2);   // 1 + e.w*c3
                v2f d01 = pk_mul(t0, t1);
                v2f d23 = pk_mul(t2, t3);
                v2f n01 = pk_fma_l(wlo, t1, pk_mul_h(wlo, t0)); // w.x*t1 + w.y*t0
                v2f n23 = pk_fma_l(whi, t3, pk_mul_h(whi, t2)); // w.z*t3 + w.w*t2
                v2f num = pk_fma(n01, d23, pk_mul(n23, d01));
                v2f den = pk_mul(d01, d23);
                v2f r;
                r.x = __builtin_amdgcn_rcpf(den.x);
                r.y = __builtin_amdgcn_rcpf(den.y);
                acc[q] = pk_fma(num, r, acc[q]);
            }
        }

        // ALL teams write partials (combine is fused into softmax)
        {
            float* dst = sP + g * 4 * K_;
#pragma unroll
            for (int q = 0; q < 4; ++q)
                *(v2f*)&dst[q * K_ + k2] = acc[q];
        }
    }
    __syncthreads();

    // ---- Phase 2: fused combine + softmax, wave w (w<4) -> q row w
    if (t < 256) {
        const int lane = t & 63;
        const int q = t >> 6;
        float sv[8];
        float m = -INFINITY;
#pragma unroll
        for (int j = 0; j < 8; ++j) {
            const int idx = q * K_ + lane + 64 * j;
            float p01 = sP[idx] + sP[4 * K_ + idx];
            float p23 = sP[8 * K_ + idx] + sP[12 * K_ + idx];
            sv[j] = -2.0f * (p01 + p23);
            m = fmaxf(m, sv[j]);
        }
#pragma unroll
        for (int off = 32; off >= 1; off >>= 1) m = fmaxf(m, __shfl_xor(m, off));
        float sum = 0.f;
#pragma unroll
        for (int j = 0; j < 8; ++j) {
            sv[j] = __builtin_amdgcn_exp2f((sv[j] - m) * LOG2E);
            sum += sv[j];
        }
#pragma unroll
        for (int off = 32; off >= 1; off >>= 1) sum += __shfl_xor(sum, off);
        float rs = 1.0f / sum;
#pragma unroll
        for (int j = 0; j < 8; ++j) sS[q * K_ + lane + 64 * j] = sv[j] * rs;
    }

    // ---- Phase 3 setup: issue first V row pair BEFORE the softmax barrier
    const int h4 = (t & 63) * 4;     // h-quad owned by this thread
    const int kq = t >> 6;           // k-16th: 32 k
    const int kbeg = kq * 32;
    const float* vb = values + (long)b * K_ * H_ + h4;

    v4f va = *(const v4f*)&vb[(kbeg + 0) * H_];
    v4f vc = *(const v4f*)&vb[(kbeg + 1) * H_];

    __syncthreads();                 // sS (softmaxed weights) ready

    // ---- Phase 3: attn @ V. thread = (h-quad, k-16th); all 4 q per thread
    {
        v4f acc0 = {0.f,0.f,0.f,0.f}, acc1 = {0.f,0.f,0.f,0.f};
        v4f acc2 = {0.f,0.f,0.f,0.f}, acc3 = {0.f,0.f,0.f,0.f};
#pragma unroll 1
        for (int k = kbeg; k < kbeg + 32; k += 4) {
            // rows k,k+1 live in va,vc; prefetch rows k+2,k+3 (always valid)
            v4f vd = *(const v4f*)&vb[(k + 2) * H_];
            v4f ve = *(const v4f*)&vb[(k + 3) * H_];
            {
                v2f a0 = *(const v2f*)&sS[0 * K_ + k];  // wave-uniform bcast
                v2f a1 = *(const v2f*)&sS[1 * K_ + k];
                v2f a2 = *(const v2f*)&sS[2 * K_ + k];
                v2f a3 = *(const v2f*)&sS[3 * K_ + k];
                acc0 = pk4_fma_l(a0, va, pk4_fma_h(a0, vc, acc0));
                acc1 = pk4_fma_l(a1, va, pk4_fma_h(a1, vc, acc1));
                acc2 = pk4_fma_l(a2, va, pk4_fma_h(a2, vc, acc2));
                acc3 = pk4_fma_l(a3, va, pk4_fma_h(a3, vc, acc3));
            }
            // rows k+2,k+3 in vd,ve; prefetch next iter's k+4,k+5 into va,vc
            if (k + 4 < kbeg + 32) {     // runtime guard
                va = *(const v4f*)&vb[(k + 4) * H_];
                vc = *(const v4f*)&vb[(k + 5) * H_];
            }
            {
                v2f a0 = *(const v2f*)&sS[0 * K_ + k + 2];
                v2f a1 = *(const v2f*)&sS[1 * K_ + k + 2];
                v2f a2 = *(const v2f*)&sS[2 * K_ + k + 2];
                v2f a3 = *(const v2f*)&sS[3 * K_ + k + 2];
                acc0 = pk4_fma_l(a0, vd, pk4_fma_h(a0, ve, acc0));
                acc1 = pk4_fma_l(a1, vd, pk4_fma_h(a1, ve, acc1));
                acc2 = pk4_fma_l(a2, vd, pk4_fma_h(a2, ve, acc2));
                acc3 = pk4_fma_l(a3, vd, pk4_fma_h(a3, ve, acc3));
            }
        }

        __syncthreads();   // all sS reads done; smem becomes sRed[16][4][256]
        float* sRed = smem;
        *(v4f*)&sRed[(kq * 4 + 0) * 256 + h4] = acc0;
        *(v4f*)&sRed[(kq * 4 + 1) * 256 + h4] = acc1;
        *(v4f*)&sRed[(kq * 4 + 2) * 256 + h4] = acc2;
        *(v4f*)&sRed[(kq * 4 + 3) * 256 + h4] = acc3;
        __syncthreads();

        // final reduce: thread t -> output (q = t>>8, h = t&255), 4-way ILP
        const int q = t >> 8;
        const int h = t & 255;
        float s0 = 0.f, s1 = 0.f, s2 = 0.f, s3 = 0.f;
#pragma unroll
        for (int kk = 0; kk < 16; kk += 4) {
            s0 += sRed[((kk + 0) * 4 + q) * 256 + h];
            s1 += sRed[((kk + 1) * 4 + q) * 256 + h];
            s2 += sRed[((kk + 2) * 4 + q) * 256 + h];
            s3 += sRed[((kk + 3) * 4 + q) * 256 + h];
        }
        out[((long)(b * Q_ + q0 + q)) * H_ + h] = (s0 + s1) + (s2 + s3);
    }
}

extern "C" void kernel_launch(void* const* d_in, const int* in_sizes, int n_in,
                              void* d_out, int out_size, void* d_ws, size_t ws_size,
                              hipStream_t stream) {
    const float* queries = (const float*)d_in[0];  // [B,Q,H]
    const float* keys    = (const float*)d_in[1];  // [B,K,H]
    const float* values  = (const float*)d_in[2];  // [B,K,H]
    const float* Wq      = (const float*)d_in[3];  // [H,H]
    const float* Wk      = (const float*)d_in[4];  // [H,H]
    const float* wv      = (const float*)d_in[5];  // [H]
    float* out = (float*)d_out;

    // ws: [qe 2MB][ke 2MB]
    float* qe = (float*)d_ws;
    float* ke = qe + QE_ELEMS;

    proj_exp<<<256, 1024, 0, stream>>>(queries, keys, Wq, Wk, qe, ke);
    attn<<<512, 1024, 0, stream>>>(qe, ke, values, wv, out);
}

// Round 12
// 110.002 us; speedup vs baseline: 1.1133x; 1.0059x over previous
//
#include <hip/hip_runtime.h>
#include <hip/hip_bf16.h>
#include <math.h>

// AdditiveAttention: B=4, Q=512, K=512, H=256, fp32.
// scores[b,q,k] = sum_h wv_h * tanh(qp + kp) -> softmax_k -> @V
// tanh(x) = 1 - 2/(1+e^{2x}); sum_h wv_h drops out of softmax.
// e^{2(q+k)} = e^{2q} * e^{2k}: exponentiate projections once (proj kernel).
// 4 h-terms share one rcp: sum wv_i/t_i = num/(t0*t1*t2*t3).
//
// R4: grid-barrier fusion => cross-XCD coherence storm. Two launches.
// R6/R8/R15: spill when LIVE set exceeds the VGPR budget; (1024,8) => 64.
//      WRITE_SIZE is the spill gate (VGPR_Count counter unreliable).
// R9: P3 q-sharing one V stream: attn 63 -> 50us (per-CU L2 BW was binding).
// R10: further V traffic cuts NEUTRAL: L2 BW off critical path.
// R11: VOP3P pk_f32 needs all operands as VGPR PAIRS; broadcast via
//      op_sel:[s,..] op_sel_hi:[s,..] on the containing pair.
// R12: packed f32 is ~issue-rate-NEUTRAL on gfx950 but halves inst count.
// R13: P3 depth-1 V prefetch: 47.1 -> 45.7us.
// R14: P3 h-quad/float4 + fused combine-softmax: 45.7 -> 41.2us.  KEEPER.
// R15/R16 lesson: all-wave softmax + deferred normalization costs MORE than
//      the 4-wave serial window it removes (44.0 vs 41.2 clean A/B).
// R17: proj_exp pk-ified: total 115 -> 110.6. attn VALU-busy (22us) now
//      MATCHES the computed instruction floor.  KEEPER.
// R18 lesson: P1 unroll-4 + P3 b128 weight loads (v4f .lo/.hi into op_sel
//      asm) SILENTLY MISCOMPILES (absmax 4.39, cause not identifiable by
//      inspection). Do not re-roll unexplained failures; reverted to R17.
// R19: exact R17 state (110.6us). attn is at its VALU instruction floor;
//      residual stall is issue-slot contention + barriers + ramp.

#define B_ 4
#define Q_ 512
#define K_ 512
#define H_ 256
#define QE_ELEMS (B_ * Q_ * H_)           // 524288
#define KE_ELEMS (B_ * H_ * K_)           // 524288

static constexpr float CEXP = 2.8853900817779268f; // 2*log2(e)
static constexpr float LOG2E = 1.4426950408889634f;

typedef float v2f __attribute__((ext_vector_type(2)));
typedef float v4f __attribute__((ext_vector_type(4)));

// d = a*b + c (both lanes, one VOP3P issue)
__device__ __forceinline__ v2f pk_fma(v2f a, v2f b, v2f c) {
    v2f d;
    asm("v_pk_fma_f32 %0, %1, %2, %3" : "=v"(d) : "v"(a), "v"(b), "v"(c));
    return d;
}
// d = {a.x,a.x}*b + c  (broadcast LO word of pair a)
__device__ __forceinline__ v2f pk_fma_l(v2f a, v2f b, v2f c) {
    v2f d;
    asm("v_pk_fma_f32 %0, %1, %2, %3 op_sel:[0,0,0] op_sel_hi:[0,1,1]"
        : "=v"(d) : "v"(a), "v"(b), "v"(c));
    return d;
}
// d = {a.y,a.y}*b + c  (broadcast HI word of pair a)
__device__ __forceinline__ v2f pk_fma_h(v2f a, v2f b, v2f c) {
    v2f d;
    asm("v_pk_fma_f32 %0, %1, %2, %3 op_sel:[1,0,0] op_sel_hi:[1,1,1]"
        : "=v"(d) : "v"(a), "v"(b), "v"(c));
    return d;
}
__device__ __forceinline__ v2f pk_mul(v2f a, v2f b) {
    v2f d;
    asm("v_pk_mul_f32 %0, %1, %2" : "=v"(d) : "v"(a), "v"(b));
    return d;
}
// d = {a.y,a.y}*b  (broadcast HI word of pair a)
__device__ __forceinline__ v2f pk_mul_h(v2f a, v2f b) {
    v2f d;
    asm("v_pk_mul_f32 %0, %1, %2 op_sel:[1,0] op_sel_hi:[1,1]"
        : "=v"(d) : "v"(a), "v"(b));
    return d;
}
// float4 forms: broadcast scalar (lo/hi word of pair a) across both halves
__device__ __forceinline__ v4f pk4_fma_l(v2f a, v4f b, v4f c) {
    v4f d;
    d.lo = pk_fma_l(a, b.lo, c.lo);
    d.hi = pk_fma_l(a, b.hi, c.hi);
    return d;
}
__device__ __forceinline__ v4f pk4_fma_h(v2f a, v4f b, v4f c) {
    v4f d;
    d.lo = pk_fma_h(a, b.lo, c.lo);
    d.hi = pk_fma_h(a, b.hi, c.hi);
    return d;
}
// tied accumulates: c += ... (no fresh dst vreg -> no RA copy)
__device__ __forceinline__ void pk_acc_l(v2f& c, v2f a, v2f b) { // c += {a.x}*b
    asm("v_pk_fma_f32 %0, %1, %2, %0 op_sel:[0,0,0] op_sel_hi:[0,1,1]"
        : "+v"(c) : "v"(a), "v"(b));
}
__device__ __forceinline__ void pk_acc_h(v2f& c, v2f a, v2f b) { // c += {a.y}*b
    asm("v_pk_fma_f32 %0, %1, %2, %0 op_sel:[1,0,0] op_sel_hi:[1,1,1]"
        : "+v"(c) : "v"(a), "v"(b));
}

// ---------------------------------------------------------------------------
// proj_exp: 256 blocks x 1024 thr. Block = one 64x64 output tile; 4 teams of
// 256 thr each reduce a 64-d quarter (double-buffered LDS, reg prefetch);
// LDS combine -> exp2 -> store.  blocks [0,128): qe; [128,256): ke[b][h][k].
// R17: inner 4x4 accumulate as 8 pk_acc (acc2[i][jp].x/.y = acc[i][2jp/2jp+1]).
// ---------------------------------------------------------------------------
#define PJ_AS(team, buf, dd, row) smem[(((team)*2 + (buf)) * 16 + (dd)) * 68 + (row)]
#define PJ_SS(team, buf, dd, row) smem[8704 + (((team)*2 + (buf)) * 16 + (dd)) * 68 + (row)]

__global__ __launch_bounds__(1024, 4) void proj_exp(
    const float* __restrict__ queries, const float* __restrict__ keys,
    const float* __restrict__ Wq, const float* __restrict__ Wk,
    float* __restrict__ qe, float* __restrict__ ke)
{
    __shared__ __align__(16) float smem[17408];   // 69632 B

    const int bid = blockIdx.x;
    const int team = threadIdx.x >> 8;   // d-quarter 0..3 (64 d each)
    const int tid = threadIdx.x & 255;

    const float* A; const float* S; float* C; int ldc;
    if (bid < 128) {                 // qe: [B*Q=2048 x H=256], 32x4 tiles
        int mt = bid >> 2, nt = bid & 3;
        A = queries + (mt * 64) * H_;
        S = Wq + (nt * 64) * H_;
        C = qe + (mt * 64) * H_ + nt * 64;
        ldc = H_;
    } else {                         // ke: per-b [H=256 x K=512], 4x8 tiles
        int id = bid - 128;
        int b = id >> 5, mt = (id >> 3) & 3, nt = id & 7;
        A = Wk + (mt * 64) * H_;
        S = keys + ((long)(b * K_ + nt * 64)) * H_;
        C = ke + ((long)(b * H_ + mt * 64)) * K_ + nt * 64;
        ldc = K_;
    }

    const int tx = tid & 15;         // n0 = tx*4
    const int ty = tid >> 4;         // m0 = ty*4
    const int ldr = tid >> 2;        // staging row 0..63
    const int ldd = (tid & 3) * 4;   // staging d-offset 0,4,8,12
    const float* GA = A + ldr * H_ + team * 64 + ldd;
    const float* GS = S + ldr * H_ + team * 64 + ldd;

    float4 av = *(const float4*)GA;
    float4 sv = *(const float4*)GS;
    PJ_AS(team, 0, ldd + 0, ldr) = av.x; PJ_AS(team, 0, ldd + 1, ldr) = av.y;
    PJ_AS(team, 0, ldd + 2, ldr) = av.z; PJ_AS(team, 0, ldd + 3, ldr) = av.w;
    PJ_SS(team, 0, ldd + 0, ldr) = sv.x; PJ_SS(team, 0, ldd + 1, ldr) = sv.y;
    PJ_SS(team, 0, ldd + 2, ldr) = sv.z; PJ_SS(team, 0, ldd + 3, ldr) = sv.w;

    v2f acc2[4][2] = {};             // acc2[i][jp] = {acc[i][2jp], acc[i][2jp+1]}
#pragma unroll
    for (int c = 0; c < 4; ++c) {    // 4 chunks x 16 d = 64 d per team
        const int cur = c & 1;
        if (c < 3) {                 // register prefetch of next chunk
            av = *(const float4*)(GA + (c + 1) * 16);
            sv = *(const float4*)(GS + (c + 1) * 16);
        }
        __syncthreads();             // buf[cur] writes visible
#pragma unroll
        for (int dd = 0; dd < 16; ++dd) {
            v4f a4 = *(const v4f*)&PJ_AS(team, cur, dd, ty * 4);
            v4f b4 = *(const v4f*)&PJ_SS(team, cur, dd, tx * 4);
            const v2f alo = a4.lo, ahi = a4.hi;
            const v2f blo = b4.lo, bhi = b4.hi;
            pk_acc_l(acc2[0][0], alo, blo); pk_acc_l(acc2[0][1], alo, bhi);
            pk_acc_h(acc2[1][0], alo, blo); pk_acc_h(acc2[1][1], alo, bhi);
            pk_acc_l(acc2[2][0], ahi, blo); pk_acc_l(acc2[2][1], ahi, bhi);
            pk_acc_h(acc2[3][0], ahi, blo); pk_acc_h(acc2[3][1], ahi, bhi);
        }
        if (c < 3) {                 // fill other buffer (last read 2 iters ago)
            const int nxt = cur ^ 1;
            PJ_AS(team, nxt, ldd + 0, ldr) = av.x;
            PJ_AS(team, nxt, ldd + 1, ldr) = av.y;
            PJ_AS(team, nxt, ldd + 2, ldr) = av.z;
            PJ_AS(team, nxt, ldd + 3, ldr) = av.w;
            PJ_SS(team, nxt, ldd + 0, ldr) = sv.x;
            PJ_SS(team, nxt, ldd + 1, ldr) = sv.y;
            PJ_SS(team, nxt, ldd + 2, ldr) = sv.z;
            PJ_SS(team, nxt, ldd + 3, ldr) = sv.w;
        }
    }

    // combine 4 d-quarter partials via LDS (reuse staging), exp, store
    __syncthreads();                 // all staging reads complete
    if (team > 0) {
        float* Cmb = smem + (team - 1) * 4352;   // 64 x 68 tile
#pragma unroll
        for (int i = 0; i < 4; ++i) {
            float4 o = {acc2[i][0].x, acc2[i][0].y, acc2[i][1].x, acc2[i][1].y};
            *(float4*)&Cmb[(ty * 4 + i) * 68 + tx * 4] = o;
        }
    }
    __syncthreads();
    if (team == 0) {
#pragma unroll
        for (int i = 0; i < 4; ++i) {
            const int off = (ty * 4 + i) * 68 + tx * 4;
            float4 p1 = *(const float4*)&smem[off];
            float4 p2 = *(const float4*)&smem[4352 + off];
            float4 p3 = *(const float4*)&smem[8704 + off];
            float4 o;
            o.x = __builtin_amdgcn_exp2f(CEXP * (acc2[i][0].x + p1.x + p2.x + p3.x));
            o.y = __builtin_amdgcn_exp2f(CEXP * (acc2[i][0].y + p1.y + p2.y + p3.y));
            o.z = __builtin_amdgcn_exp2f(CEXP * (acc2[i][1].x + p1.z + p2.z + p3.z));
            o.w = __builtin_amdgcn_exp2f(CEXP * (acc2[i][1].y + p1.w + p2.w + p3.w));
            *(float4*)&C[(ty * 4 + i) * ldc + tx * 4] = o;
        }
    }
}

// ---------------------------------------------------------------------------
// attn (R14/R17 KEEPER, 41.2-41.5us): 512 blocks x 1024 thr (16 waves;
// 64-VGPR budget => 2 blocks/CU). XCD-affine: bid%8 -> XCD; pair = batch b.
// Phase 1: thread = (k-pair, h-quarter); pk math; unroll 2; ALL teams
//          write sP.
// Phase 2: fused combine+softmax: wave w<4 -> q row w, reads 4 sP partials.
// Phase 3: thread = (h-quad, kq/16); float4 V stream, named-reg depth-1
//          prefetch; v2f weight loads; 16 kq-partials ->
//          sRed[16][4][256] = 64KB LDS reduce.
// ---------------------------------------------------------------------------
__global__ __launch_bounds__(1024, 8) void attn(
    const float* __restrict__ qe, const float* __restrict__ ke,
    const float* __restrict__ values, const float* __restrict__ wv,
    float* __restrict__ out)
{
    const int bid = blockIdx.x;
    const int xcd = bid & 7;
    const int b = xcd >> 1;
    const int q0 = (((bid >> 3) << 1) | (xcd & 1)) * 4;
    const int t = threadIdx.x;

    // flat LDS 64KB. P1/P2 view: sQ[4*256] | wvs[256] | sS[4*512] | sP[4][4*512]
    //                P3 reduce view: sRed[16][4][256] (aliases everything)
    __shared__ __align__(16) float smem[16384];
    float* sQ  = smem;                   // [4][H_]
    float* wvs = smem + 4 * H_;          // [H_]
    float* sS  = smem + 5 * H_;          // [4][K_]
    float* sP  = smem + 5 * H_ + 4 * K_; // [4][4][K_]

    sQ[t] = qe[((long)(b * Q_ + q0 + (t >> 8))) * H_ + (t & 255)];
    if (t < H_) wvs[t] = wv[t];
    __syncthreads();

    // ---- Phase 1: scores
    {
        const int k2 = (t & 255) * 2;    // owns k2, k2+1 (contiguous)
        const int g = t >> 8;            // h-quarter: h in [g*64, g*64+64)
        const float* keb = ke + ((long)(b * H_ + g * 64)) * K_ + k2;

        v2f nx0 = *(const v2f*)(keb);
        v2f nx1 = *(const v2f*)(keb + K_);
        v2f nx2 = *(const v2f*)(keb + 2 * K_);
        v2f nx3 = *(const v2f*)(keb + 3 * K_);
        v2f acc[4] = {{0.f,0.f},{0.f,0.f},{0.f,0.f},{0.f,0.f}};
        const v2f one2 = {1.0f, 1.0f};

#pragma unroll 2
        for (int hl = 0; hl < 64; hl += 4) {
            v2f c0 = nx0, c1 = nx1, c2 = nx2, c3 = nx3;
            if (hl < 60) {               // depth-1 prefetch (runtime guard)
                const float* p = keb + (hl + 4) * K_;
                nx0 = *(const v2f*)(p);
                nx1 = *(const v2f*)(p + K_);
                nx2 = *(const v2f*)(p + 2 * K_);
                nx3 = *(const v2f*)(p + 3 * K_);
            }
            const int h = g * 64 + hl;
            v4f w4 = *(const v4f*)&wvs[h];
            const v2f wlo = w4.lo, whi = w4.hi;
#pragma unroll
            for (int q = 0; q < 4; ++q) {
                v4f e = *(const v4f*)&sQ[q * H_ + h];
                const v2f elo = e.lo, ehi = e.hi;
                v2f t0 = pk_fma_l(elo, c0, one2);   // 1 + e.x*c0
                v2f t1 = pk_fma_h(elo, c1, one2);   // 1 + e.y*c1
                v2f t2 = pk_fma_l(ehi, c2, one2);   // 1 + e.z*c2
                v2f t3 = pk_fma_h(ehi, c3, one2);   // 1 + e.w*c3
                v2f d01 = pk_mul(t0, t1);
                v2f d23 = pk_mul(t2, t3);
                v2f n01 = pk_fma_l(wlo, t1, pk_mul_h(wlo, t0)); // w.x*t1 + w.y*t0
                v2f n23 = pk_fma_l(whi, t3, pk_mul_h(whi, t2)); // w.z*t3 + w.w*t2
                v2f num = pk_fma(n01, d23, pk_mul(n23, d01));
                v2f den = pk_mul(d01, d23);
                v2f r;
                r.x = __builtin_amdgcn_rcpf(den.x);
                r.y = __builtin_amdgcn_rcpf(den.y);
                acc[q] = pk_fma(num, r, acc[q]);
            }
        }

        // ALL teams write partials (combine is fused into softmax)
        {
            float* dst = sP + g * 4 * K_;
#pragma unroll
            for (int q = 0; q < 4; ++q)
                *(v2f*)&dst[q * K_ + k2] = acc[q];
        }
    }
    __syncthreads();

    // ---- Phase 2: fused combine + softmax, wave w (w<4) -> q row w
    if (t < 256) {
        const int lane = t & 63;
        const int q = t >> 6;
        float sv[8];
        float m = -INFINITY;
#pragma unroll
        for (int j = 0; j < 8; ++j) {
            const int idx = q * K_ + lane + 64 * j;
            float p01 = sP[idx] + sP[4 * K_ + idx];
            float p23 = sP[8 * K_ + idx] + sP[12 * K_ + idx];
            sv[j] = -2.0f * (p01 + p23);
            m = fmaxf(m, sv[j]);
        }
#pragma unroll
        for (int off = 32; off >= 1; off >>= 1) m = fmaxf(m, __shfl_xor(m, off));
        float sum = 0.f;
#pragma unroll
        for (int j = 0; j < 8; ++j) {
            sv[j] = __builtin_amdgcn_exp2f((sv[j] - m) * LOG2E);
            sum += sv[j];
        }
#pragma unroll
        for (int off = 32; off >= 1; off >>= 1) sum += __shfl_xor(sum, off);
        float rs = 1.0f / sum;
#pragma unroll
        for (int j = 0; j < 8; ++j) sS[q * K_ + lane + 64 * j] = sv[j] * rs;
    }

    // ---- Phase 3 setup: issue first V row pair BEFORE the softmax barrier
    const int h4 = (t & 63) * 4;     // h-quad owned by this thread
    const int kq = t >> 6;           // k-16th: 32 k
    const int kbeg = kq * 32;
    const float* vb = values + (long)b * K_ * H_ + h4;

    v4f va = *(const v4f*)&vb[(kbeg + 0) * H_];
    v4f vc = *(const v4f*)&vb[(kbeg + 1) * H_];

    __syncthreads();                 // sS (softmaxed weights) ready

    // ---- Phase 3: attn @ V. thread = (h-quad, k-16th); all 4 q per thread
    {
        v4f acc0 = {0.f,0.f,0.f,0.f}, acc1 = {0.f,0.f,0.f,0.f};
        v4f acc2 = {0.f,0.f,0.f,0.f}, acc3 = {0.f,0.f,0.f,0.f};
#pragma unroll 1
        for (int k = kbeg; k < kbeg + 32; k += 4) {
            // rows k,k+1 live in va,vc; prefetch rows k+2,k+3 (always valid)
            v4f vd = *(const v4f*)&vb[(k + 2) * H_];
            v4f ve = *(const v4f*)&vb[(k + 3) * H_];
            {
                v2f a0 = *(const v2f*)&sS[0 * K_ + k];  // wave-uniform bcast
                v2f a1 = *(const v2f*)&sS[1 * K_ + k];
                v2f a2 = *(const v2f*)&sS[2 * K_ + k];
                v2f a3 = *(const v2f*)&sS[3 * K_ + k];
                acc0 = pk4_fma_l(a0, va, pk4_fma_h(a0, vc, acc0));
                acc1 = pk4_fma_l(a1, va, pk4_fma_h(a1, vc, acc1));
                acc2 = pk4_fma_l(a2, va, pk4_fma_h(a2, vc, acc2));
                acc3 = pk4_fma_l(a3, va, pk4_fma_h(a3, vc, acc3));
            }
            // rows k+2,k+3 in vd,ve; prefetch next iter's k+4,k+5 into va,vc
            if (k + 4 < kbeg + 32) {     // runtime guard
                va = *(const v4f*)&vb[(k + 4) * H_];
                vc = *(const v4f*)&vb[(k + 5) * H_];
            }
            {
                v2f a0 = *(const v2f*)&sS[0 * K_ + k + 2];
                v2f a1 = *(const v2f*)&sS[1 * K_ + k + 2];
                v2f a2 = *(const v2f*)&sS[2 * K_ + k + 2];
                v2f a3 = *(const v2f*)&sS[3 * K_ + k + 2];
                acc0 = pk4_fma_l(a0, vd, pk4_fma_h(a0, ve, acc0));
                acc1 = pk4_fma_l(a1, vd, pk4_fma_h(a1, ve, acc1));
                acc2 = pk4_fma_l(a2, vd, pk4_fma_h(a2, ve, acc2));
                acc3 = pk4_fma_l(a3, vd, pk4_fma_h(a3, ve, acc3));
            }
        }

        __syncthreads();   // all sS reads done; smem becomes sRed[16][4][256]
        float* sRed = smem;
        *(v4f*)&sRed[(kq * 4 + 0) * 256 + h4] = acc0;
        *(v4f*)&sRed[(kq * 4 + 1) * 256 + h4] = acc1;
        *(v4f*)&sRed[(kq * 4 + 2) * 256 + h4] = acc2;
        *(v4f*)&sRed[(kq * 4 + 3) * 256 + h4] = acc3;
        __syncthreads();

        // final reduce: thread t -> output (q = t>>8, h = t&255), 4-way ILP
        const int q = t >> 8;
        const int h = t & 255;
        float s0 = 0.f, s1 = 0.f, s2 = 0.f, s3 = 0.f;
#pragma unroll
        for (int kk = 0; kk < 16; kk += 4) {
            s0 += sRed[((kk + 0) * 4 + q) * 256 + h];
            s1 += sRed[((kk + 1) * 4 + q) * 256 + h];
            s2 += sRed[((kk + 2) * 4 + q) * 256 + h];
            s3 += sRed[((kk + 3) * 4 + q) * 256 + h];
        }
        out[((long)(b * Q_ + q0 + q)) * H_ + h] = (s0 + s1) + (s2 + s3);
    }
}

extern "C" void kernel_launch(void* const* d_in, const int* in_sizes, int n_in,
                              void* d_out, int out_size, void* d_ws, size_t ws_size,
                              hipStream_t stream) {
    const float* queries = (const float*)d_in[0];  // [B,Q,H]
    const float* keys    = (const float*)d_in[1];  // [B,K,H]
    const float* values  = (const float*)d_in[2];  // [B,K,H]
    const float* Wq      = (const float*)d_in[3];  // [H,H]
    const float* Wk      = (const float*)d_in[4];  // [H,H]
    const float* wv      = (const float*)d_in[5];  // [H]
    float* out = (float*)d_out;

    // ws: [qe 2MB][ke 2MB]
    float* qe = (float*)d_ws;
    float* ke = qe + QE_ELEMS;

    proj_exp<<<256, 1024, 0, stream>>>(queries, keys, Wq, Wk, qe, ke);
    attn<<<512, 1024, 0, stream>>>(qe, ke, values, wv, out);
}